// Round 1
// 345.014 us; speedup vs baseline: 1.0164x; 1.0164x over previous
//
#include <hip/hip_runtime.h>
#include <hip/hip_bf16.h>

// Problem constants
#define Bn 16
#define Cc 512
#define Ss 1024           // H*W tokens per batch
#define HEADS 8
#define DHEAD 64
#define GROUPS 32
#define CPG 16
#define EPSv 1e-5f
#define Mtok (Bn*Ss)      // 16384 token rows
#define QKVS 1536         // fused qkv row stride
#define PROW 34           // padded image row (32 + halo)
#define PIMG (PROW*PROW)  // 1156 padded tokens per batch

typedef __hip_bfloat16 bf16;
typedef __attribute__((ext_vector_type(8))) short short8;   // MFMA A/B frag (8 bf16)
typedef __attribute__((ext_vector_type(4))) float f32x4;    // MFMA C/D frag

union U4 { uint4 u; bf16 h[8]; };
union B4 { ushort4 u; bf16 h[4]; };

// async global->LDS, 16 B/lane; LDS dest = wave-uniform base + lane*16
__device__ __forceinline__ void stage16(const bf16* g, bf16* l) {
    __builtin_amdgcn_global_load_lds((const __attribute__((address_space(1))) void*)g,
                                     (__attribute__((address_space(3))) void*)l,
                                     16, 0, 0);
}

// ---------------------------------------------------------------------------
// 0) Weight transpose+convert: src f32 [512][512] (k-major) -> dst bf16 [n][k]
// ---------------------------------------------------------------------------
__global__ __launch_bounds__(256) void wtrans(const float* __restrict__ src,
                                              bf16* __restrict__ dst) {
    size_t off = (size_t)blockIdx.y * 262144;
    int t = blockIdx.x * 256 + threadIdx.x;     // 0..32767
    int n = t & 511, k8 = (t >> 9) * 8;
    const float* s = src + off + (size_t)k8 * 512 + n;
    U4 o;
#pragma unroll
    for (int j = 0; j < 8; j++) o.h[j] = __float2bfloat16(s[(size_t)j * 512]);
    *(uint4*)(dst + off + (size_t)n * 512 + k8) = o.u;
}

// ---------------------------------------------------------------------------
// 1) GroupNorm stats
// ---------------------------------------------------------------------------
__global__ __launch_bounds__(256) void gn_stats(const float* __restrict__ x,
                                                float* __restrict__ stats) {
    int bg = blockIdx.x;
    int b = bg >> 5, g = bg & 31;
    int tid = threadIdx.x;
    const size_t base = (size_t)b * Ss * Cc + g * CPG;
    float sum = 0.f, sq = 0.f;
    for (int i = tid; i < 4096; i += 256) {
        int s = i >> 2, c4 = (i & 3) * 4;
        float4 t = *(const float4*)(x + base + (size_t)s * Cc + c4);
        sum += t.x + t.y + t.z + t.w;
        sq  += t.x * t.x + t.y * t.y + t.z * t.z + t.w * t.w;
    }
    __shared__ float s1[4], s2[4];
#pragma unroll
    for (int off = 32; off > 0; off >>= 1) {
        sum += __shfl_down(sum, off);
        sq  += __shfl_down(sq,  off);
    }
    if ((tid & 63) == 0) { s1[tid >> 6] = sum; s2[tid >> 6] = sq; }
    __syncthreads();
    if (tid == 0) {
        float S = s1[0] + s1[1] + s1[2] + s1[3];
        float Q = s2[0] + s2[1] + s2[2] + s2[3];
        float mean = S * (1.f / 16384.f);
        float var  = Q * (1.f / 16384.f) - mean * mean;
        stats[bg * 2 + 0] = mean;
        stats[bg * 2 + 1] = rsqrtf(var + EPSv);
    }
}

// ---------------------------------------------------------------------------
// 2) GroupNorm apply (f32 in, bf16 out)
// ---------------------------------------------------------------------------
__global__ __launch_bounds__(256) void gn_apply(const float* __restrict__ x,
                                                const float* __restrict__ stats,
                                                const float* __restrict__ gamma,
                                                const float* __restrict__ beta,
                                                bf16* __restrict__ xn) {
    size_t i = (size_t)blockIdx.x * 256 + threadIdx.x;
    size_t e = i * 4;
    int c0 = (int)(e & (Cc - 1));
    int token = (int)(e >> 9);
    int b = token >> 10;
    int g = c0 >> 4;
    float mean = stats[(b * 32 + g) * 2 + 0];
    float rstd = stats[(b * 32 + g) * 2 + 1];
    float4 t  = *(const float4*)(x + e);
    float4 gm = *(const float4*)(gamma + c0);
    float4 bt = *(const float4*)(beta + c0);
    B4 o;
    o.h[0] = __float2bfloat16((t.x - mean) * rstd * gm.x + bt.x);
    o.h[1] = __float2bfloat16((t.y - mean) * rstd * gm.y + bt.y);
    o.h[2] = __float2bfloat16((t.z - mean) * rstd * gm.z + bt.z);
    o.h[3] = __float2bfloat16((t.w - mean) * rstd * gm.w + bt.w);
    *(ushort4*)(xn + e) = o.u;
}

// ---------------------------------------------------------------------------
// 2b) Zero the padded-activation border (132 border tokens x 512 ch x 16 b)
// ---------------------------------------------------------------------------
__global__ __launch_bounds__(256) void zero_pad(bf16* __restrict__ Pad) {
    int idx = blockIdx.x * 256 + threadIdx.x;     // exactly 16*132*64
    int b = idx / (132 * 64);
    int rem = idx - b * 132 * 64;
    int t = rem >> 6, seg = rem & 63;
    int r, c;
    if (t < 34)      { r = 0;  c = t; }
    else if (t < 68) { r = 33; c = t - 34; }
    else { int u = t - 68; r = 1 + (u >> 1); c = (u & 1) * 33; }
    uint4 z = {0u, 0u, 0u, 0u};
    *(uint4*)(Pad + ((size_t)b * PIMG + r * PROW + c) * Cc + seg * 8) = z;
}

// ---------------------------------------------------------------------------
// 3) Fused QKV GEMM, m97-style: 128x128 tile, global_load_lds staging,
//    ds_read_b128 frags, 16 MFMA / wave / k-step.
//    C[16384,1536] = A[16384,512] @ Wt^T  (Wt is [n][k] bf16)
// ---------------------------------------------------------------------------
__global__ __launch_bounds__(256) void gemm_qkv(const bf16* __restrict__ A,
                                                const bf16* __restrict__ Wt,
                                                bf16* __restrict__ C) {
    __shared__ __align__(16) bf16 As[128][32];
    __shared__ __align__(16) bf16 Bs[128][32];
    int tid = threadIdx.x;
    int wave = tid >> 6, lane = tid & 63;
    int l15 = lane & 15, quad = lane >> 4;
    int wm = wave >> 1, wn = wave & 1;
    int m0 = blockIdx.y * 128, n0 = blockIdx.x * 128;
    int lr = lane >> 2, kseg = (lane & 3) * 8;
    int ar0 = wave * 32 + lr;                      // tile row staged by this lane

    const bf16* ga = A  + (size_t)(m0 + ar0) * Cc + kseg;
    const bf16* gb = Wt + (size_t)(n0 + ar0) * Cc + kseg;
    bf16* la0 = &As[wave * 32][0];
    bf16* la1 = &As[wave * 32 + 16][0];
    bf16* lb0 = &Bs[wave * 32][0];
    bf16* lb1 = &Bs[wave * 32 + 16][0];

    f32x4 acc[4][4] = {};
    for (int k0 = 0; k0 < 512; k0 += 32) {
        __syncthreads();
        stage16(ga + k0,                  la0);
        stage16(ga + k0 + (size_t)16 * Cc, la1);
        stage16(gb + k0,                  lb0);
        stage16(gb + k0 + (size_t)16 * Cc, lb1);
        __syncthreads();
        short8 af[4], bfv[4];
#pragma unroll
        for (int mt = 0; mt < 4; mt++) af[mt]  = *(const short8*)&As[wm * 64 + mt * 16 + l15][quad * 8];
#pragma unroll
        for (int nt = 0; nt < 4; nt++) bfv[nt] = *(const short8*)&Bs[wn * 64 + nt * 16 + l15][quad * 8];
#pragma unroll
        for (int mt = 0; mt < 4; mt++)
#pragma unroll
            for (int nt = 0; nt < 4; nt++)
                acc[mt][nt] = __builtin_amdgcn_mfma_f32_16x16x32_bf16(af[mt], bfv[nt], acc[mt][nt], 0, 0, 0);
    }
#pragma unroll
    for (int mt = 0; mt < 4; mt++)
#pragma unroll
        for (int r = 0; r < 4; r++) {
            size_t row = (size_t)(m0 + wm * 64 + mt * 16 + quad * 4 + r) * QKVS + n0 + wn * 64 + l15;
#pragma unroll
            for (int nt = 0; nt < 4; nt++)
                C[row + nt * 16] = __float2bfloat16(acc[mt][nt][r]);
        }
}

// ---------------------------------------------------------------------------
// 4) Flash-style MFMA attention (unchanged math); output -> padded buffer
// ---------------------------------------------------------------------------
__global__ __launch_bounds__(256) void attention_mfma(const bf16* __restrict__ QKV,
                                                      bf16* __restrict__ Pad) {
    int blk = blockIdx.x;
    int qt = blk & 15;
    int bh = blk >> 4;
    int h = bh & (HEADS - 1), b = bh >> 3;
    int tid = threadIdx.x;
    int wave = tid >> 6, lane = tid & 63;
    int l15 = lane & 15, quad = lane >> 4;

    __shared__ __align__(16) bf16 Ks[2][32][72];
    __shared__ __align__(16) bf16 Vt[2][64][40];
    __shared__ __align__(16) bf16 Ps[4][16][40];

    const size_t base = (size_t)b * Ss * QKVS + h * DHEAD;
    const bf16* kbase = QKV + base + 512;
    const bf16* vbase = QKV + base + 1024;

    int q0 = qt * 64 + wave * 16;
    const bf16* qrow = QKV + base + (size_t)(q0 + l15) * QKVS + quad * 8;
    short8 qf0 = *(const short8*)(qrow);
    short8 qf1 = *(const short8*)(qrow + 32);

    f32x4 oacc[4] = {{0.f,0.f,0.f,0.f},{0.f,0.f,0.f,0.f},{0.f,0.f,0.f,0.f},{0.f,0.f,0.f,0.f}};
    float lsum[4] = {0.f, 0.f, 0.f, 0.f};
    const f32x4 zero4 = {0.f, 0.f, 0.f, 0.f};

    int tok = tid & 31, d0 = (tid >> 5) * 8;

    uint4 nk, nv;
    {
        const size_t rb = (size_t)tok * QKVS + d0;
        nk = *(const uint4*)(kbase + rb);
        nv = *(const uint4*)(vbase + rb);
    }
    *(uint4*)&Ks[0][tok][d0] = nk;
    { U4 u; u.u = nv;
#pragma unroll
      for (int i = 0; i < 8; i++) Vt[0][d0 + i][tok] = u.h[i]; }
    __syncthreads();

    for (int c = 0; c < 32; ++c) {
        int buf = c & 1;
        if (c + 1 < 32) {
            const size_t rb = (size_t)((c + 1) * 32 + tok) * QKVS + d0;
            nk = *(const uint4*)(kbase + rb);
            nv = *(const uint4*)(vbase + rb);
        }
#pragma unroll
        for (int kg = 0; kg < 2; kg++) {
            short8 kf0 = *(const short8*)&Ks[buf][kg * 16 + l15][quad * 8];
            short8 kf1 = *(const short8*)&Ks[buf][kg * 16 + l15][32 + quad * 8];
            f32x4 s = __builtin_amdgcn_mfma_f32_16x16x32_bf16(qf0, kf0, zero4, 0, 0, 0);
            s = __builtin_amdgcn_mfma_f32_16x16x32_bf16(qf1, kf1, s, 0, 0, 0);
#pragma unroll
            for (int r = 0; r < 4; r++) {
                float p = __expf(s[r] * 0.125f);
                lsum[r] += p;
                Ps[wave][quad * 4 + r][kg * 16 + l15] = __float2bfloat16(p);
            }
        }
        short8 pf = *(const short8*)&Ps[wave][l15][quad * 8];
#pragma unroll
        for (int dt = 0; dt < 4; dt++) {
            short8 vf = *(const short8*)&Vt[buf][dt * 16 + l15][quad * 8];
            oacc[dt] = __builtin_amdgcn_mfma_f32_16x16x32_bf16(pf, vf, oacc[dt], 0, 0, 0);
        }
        if (c + 1 < 32) {
            *(uint4*)&Ks[buf ^ 1][tok][d0] = nk;
            U4 u; u.u = nv;
#pragma unroll
            for (int i = 0; i < 8; i++) Vt[buf ^ 1][d0 + i][tok] = u.h[i];
        }
        __syncthreads();
    }

#pragma unroll
    for (int r = 0; r < 4; r++) {
#pragma unroll
        for (int m = 1; m < 16; m <<= 1) lsum[r] += __shfl_xor(lsum[r], m);
    }
#pragma unroll
    for (int r = 0; r < 4; r++) {
        float inv = 1.f / lsum[r];
        int s = q0 + quad * 4 + r;
        size_t rowoff = ((size_t)(b * PROW + (s >> 5) + 1) * PROW + (s & 31) + 1) * Cc + h * DHEAD;
#pragma unroll
        for (int dt = 0; dt < 4; dt++)
            Pad[rowoff + dt * 16 + l15] = __float2bfloat16(oacc[dt][r] * inv);
    }
}

// ---------------------------------------------------------------------------
// 5) 3x3 conv as implicit GEMM with dx-tap sharing:
//    per dy (3), stage a [4 rows][34 cols][32 k] halo A-tile ONCE plus the
//    3 dx weight tiles; the 3 dx taps become LDS column-shifted reads.
//    48 stage/barrier iterations (was 144), 48 MFMA/wave per barrier (was 16).
//    K = 9 taps x 512; + bias + residual, f32 out.
// ---------------------------------------------------------------------------
__global__ __launch_bounds__(256) void conv_mfma(const bf16* __restrict__ Pad,
                                                 const bf16* __restrict__ Wct,
                                                 const float* __restrict__ bias,
                                                 const float* __restrict__ xres,
                                                 float* __restrict__ out) {
    // A halo tile: 4 image rows x 34 padded cols x 32 k = 136 rows x 64 B (8704 B)
    __shared__ __align__(16) bf16 As[136 * 32];
    // B tiles for the 3 dx taps of the current dy: 24576 B
    __shared__ __align__(16) bf16 Bs[3][128][32];

    int tid = threadIdx.x;
    int wave = tid >> 6, lane = tid & 63;
    int l15 = lane & 15, quad = lane >> 4;
    int wm = wave >> 1, wn = wave & 1;
    int m0 = blockIdx.y * 128, n0 = blockIdx.x * 128;

    int b = m0 >> 10, oh0 = (m0 & 1023) >> 5;      // block = 4 image rows of one batch

    // ---- B staging geometry (per wave: rows wave*32..+31, as in gemm_qkv) ----
    int lr = lane >> 2, kseg = (lane & 3) * 8;
    const bf16* gwp = Wct + (size_t)(n0 + wave * 32 + lr) * Cc + kseg;

    // ---- A staging geometry: linear chunks c = tid, tid+256, tid+512(<544) ----
    // chunk c (16 B) -> token t=c>>2 (r=t/34, col=t%34), k-slot (c&3)*8;
    // LDS dest byte = c*16 (linear => global_load_lds-compatible)
    int t1 = tid >> 2,          r1 = t1 / 34, col1 = t1 - r1 * 34;
    int t2 = (tid + 256) >> 2,  r2 = t2 / 34, col2 = t2 - r2 * 34;
    int t3 = (tid + 512) >> 2,  r3 = t3 / 34, col3 = t3 - r3 * 34;
    int ks = (tid & 3) * 8;                         // same for all three rounds
    const size_t dyStride = (size_t)PROW * Cc;
    size_t pa1 = ((size_t)b * PIMG + (size_t)(oh0 + r1) * PROW + col1) * Cc + ks;
    size_t pa2 = ((size_t)b * PIMG + (size_t)(oh0 + r2) * PROW + col2) * Cc + ks;
    size_t pa3 = ((size_t)b * PIMG + (size_t)(oh0 + r3) * PROW + col3) * Cc + ks;
    bf16* aB0 = As + wave * 512;                    // round-0 chunks: wave*64+lane
    bf16* aB1 = As + 2048 + wave * 512;             // round-1 chunks
    bf16* aB2 = As + 4096;                          // round-2 chunks (wave 0, lane<32)

    // ---- A fragment row bases: output row rr = wm*2+(mt>>1), ow = (mt&1)*16+l15
    int arow[4];
#pragma unroll
    for (int mt = 0; mt < 4; mt++)
        arow[mt] = (wm * 2 + (mt >> 1)) * 34 + (mt & 1) * 16 + l15;

    f32x4 acc[4][4] = {};
    for (int dyi = 0; dyi < 3; ++dyi) {             // dy = dyi-1
        const bf16* gA = Pad + (size_t)dyi * dyStride;
        const bf16* gW = gwp + (size_t)(dyi * 3) * (Cc * Cc);
        for (int k0 = 0; k0 < 512; k0 += 32) {
            __syncthreads();
            stage16(gA + pa1 + k0, aB0);
            stage16(gA + pa2 + k0, aB1);
            if (tid < 32) stage16(gA + pa3 + k0, aB2);
#pragma unroll
            for (int t = 0; t < 3; t++) {
                const bf16* gwt = gW + (size_t)t * (Cc * Cc) + k0;
                stage16(gwt,                   &Bs[t][wave * 32][0]);
                stage16(gwt + (size_t)16 * Cc, &Bs[t][wave * 32 + 16][0]);
            }
            __syncthreads();
#pragma unroll
            for (int dxi = 0; dxi < 3; dxi++) {
                short8 af[4], bfv[4];
#pragma unroll
                for (int mt = 0; mt < 4; mt++)
                    af[mt] = *(const short8*)&As[(arow[mt] + dxi) * 32 + quad * 8];
#pragma unroll
                for (int nt = 0; nt < 4; nt++)
                    bfv[nt] = *(const short8*)&Bs[dxi][wn * 64 + nt * 16 + l15][quad * 8];
#pragma unroll
                for (int mt = 0; mt < 4; mt++)
#pragma unroll
                    for (int nt = 0; nt < 4; nt++)
                        acc[mt][nt] = __builtin_amdgcn_mfma_f32_16x16x32_bf16(af[mt], bfv[nt], acc[mt][nt], 0, 0, 0);
            }
        }
    }
#pragma unroll
    for (int mt = 0; mt < 4; mt++)
#pragma unroll
        for (int r = 0; r < 4; r++) {
            size_t row = (size_t)(m0 + wm * 64 + mt * 16 + quad * 4 + r) * Cc + n0 + wn * 64 + l15;
#pragma unroll
            for (int nt = 0; nt < 4; nt++) {
                int n = n0 + wn * 64 + nt * 16 + l15;
                out[row + nt * 16] = acc[mt][nt][r] + bias[n] + xres[row + nt * 16];
            }
        }
}

// ---------------------------------------------------------------------------
extern "C" void kernel_launch(void* const* d_in, const int* in_sizes, int n_in,
                              void* d_out, int out_size, void* d_ws, size_t ws_size,
                              hipStream_t stream) {
    const float* x     = (const float*)d_in[0];
    const float* gamma = (const float*)d_in[1];
    const float* beta  = (const float*)d_in[2];
    const float* wq    = (const float*)d_in[3];
    const float* wk    = (const float*)d_in[4];
    const float* wv    = (const float*)d_in[5];
    const float* convw = (const float*)d_in[6];
    const float* convb = (const float*)d_in[7];
    float* out = (float*)d_out;

    // ws layout (time-multiplexed; peak ~71.5 MiB):
    //   [0, 18.9 MiB)  : pad   (written by zero_pad+attention AFTER gemm_qkv)
    //   [0, 4 KiB)     : stats (dead before pad is written)
    //   [4 KiB, +16MiB): xn    (dead before pad is written)
    //   [xn end, +1.5M): wt    (dead before pad is written)
    //   [19 MiB, +48M) : qkv
    //   [67 MiB, +4.5M): wct
    char* ws = (char*)d_ws;
    bf16*  pad   = (bf16*)ws;
    float* stats = (float*)ws;
    bf16*  xn    = (bf16*)(ws + 4096);
    bf16*  wt    = (bf16*)(ws + 4096 + ((size_t)16 << 20));
    bf16*  qkv   = (bf16*)(ws + ((size_t)19 << 20));
    bf16*  wct   = (bf16*)(ws + ((size_t)67 << 20));

    // weight prep (dst regions distinct from src-time-live data)
    wtrans<<<dim3(128, 1), 256, 0, stream>>>(wq, wt);
    wtrans<<<dim3(128, 1), 256, 0, stream>>>(wk, wt + 262144);
    wtrans<<<dim3(128, 1), 256, 0, stream>>>(wv, wt + 524288);
    wtrans<<<dim3(128, 9), 256, 0, stream>>>(convw, wct);

    gn_stats<<<dim3(Bn * GROUPS), 256, 0, stream>>>(x, stats);
    gn_apply<<<dim3(Mtok * Cc / (4 * 256)), 256, 0, stream>>>(x, stats, gamma, beta, xn);

    gemm_qkv<<<dim3(QKVS / 128, Mtok / 128), 256, 0, stream>>>(xn, wt, qkv);

    zero_pad<<<dim3(528), 256, 0, stream>>>(pad);   // after gemm_qkv: region overlaps xn/wt
    attention_mfma<<<dim3(Bn * HEADS * (Ss / 64)), 256, 0, stream>>>(qkv, pad);

    conv_mfma<<<dim3(Cc / 128, Mtok / 128), 256, 0, stream>>>(pad, wct, convb, x, out);
}

// Round 2
// 321.498 us; speedup vs baseline: 1.0907x; 1.0731x over previous
//
#include <hip/hip_runtime.h>
#include <hip/hip_bf16.h>

// Problem constants
#define Bn 16
#define Cc 512
#define Ss 1024           // H*W tokens per batch
#define HEADS 8
#define DHEAD 64
#define GROUPS 32
#define CPG 16
#define EPSv 1e-5f
#define Mtok (Bn*Ss)      // 16384 token rows
#define QKVS 1536         // fused qkv row stride
#define PROW 34           // padded image row (32 + halo)
#define PIMG (PROW*PROW)  // 1156 padded tokens per batch

typedef __hip_bfloat16 bf16;
typedef __attribute__((ext_vector_type(8))) short short8;   // MFMA A/B frag (8 bf16)
typedef __attribute__((ext_vector_type(4))) float f32x4;    // MFMA C/D frag

union U4 { uint4 u; bf16 h[8]; };
union B4 { ushort4 u; bf16 h[4]; };

// async global->LDS, 16 B/lane; LDS dest = wave-uniform base + lane*16
__device__ __forceinline__ void stage16(const bf16* g, bf16* l) {
    __builtin_amdgcn_global_load_lds((const __attribute__((address_space(1))) void*)g,
                                     (__attribute__((address_space(3))) void*)l,
                                     16, 0, 0);
}

// ---------------------------------------------------------------------------
// 0) Weight transpose+convert: src f32 [512][512] (k-major) -> dst bf16 [n][k]
// ---------------------------------------------------------------------------
__global__ __launch_bounds__(256) void wtrans(const float* __restrict__ src,
                                              bf16* __restrict__ dst) {
    size_t off = (size_t)blockIdx.y * 262144;
    int t = blockIdx.x * 256 + threadIdx.x;     // 0..32767
    int n = t & 511, k8 = (t >> 9) * 8;
    const float* s = src + off + (size_t)k8 * 512 + n;
    U4 o;
#pragma unroll
    for (int j = 0; j < 8; j++) o.h[j] = __float2bfloat16(s[(size_t)j * 512]);
    *(uint4*)(dst + off + (size_t)n * 512 + k8) = o.u;
}

// ---------------------------------------------------------------------------
// 1) GroupNorm stats
// ---------------------------------------------------------------------------
__global__ __launch_bounds__(256) void gn_stats(const float* __restrict__ x,
                                                float* __restrict__ stats) {
    int bg = blockIdx.x;
    int b = bg >> 5, g = bg & 31;
    int tid = threadIdx.x;
    const size_t base = (size_t)b * Ss * Cc + g * CPG;
    float sum = 0.f, sq = 0.f;
    for (int i = tid; i < 4096; i += 256) {
        int s = i >> 2, c4 = (i & 3) * 4;
        float4 t = *(const float4*)(x + base + (size_t)s * Cc + c4);
        sum += t.x + t.y + t.z + t.w;
        sq  += t.x * t.x + t.y * t.y + t.z * t.z + t.w * t.w;
    }
    __shared__ float s1[4], s2[4];
#pragma unroll
    for (int off = 32; off > 0; off >>= 1) {
        sum += __shfl_down(sum, off);
        sq  += __shfl_down(sq,  off);
    }
    if ((tid & 63) == 0) { s1[tid >> 6] = sum; s2[tid >> 6] = sq; }
    __syncthreads();
    if (tid == 0) {
        float S = s1[0] + s1[1] + s1[2] + s1[3];
        float Q = s2[0] + s2[1] + s2[2] + s2[3];
        float mean = S * (1.f / 16384.f);
        float var  = Q * (1.f / 16384.f) - mean * mean;
        stats[bg * 2 + 0] = mean;
        stats[bg * 2 + 1] = rsqrtf(var + EPSv);
    }
}

// ---------------------------------------------------------------------------
// 2) GroupNorm apply (f32 in, bf16 out)
// ---------------------------------------------------------------------------
__global__ __launch_bounds__(256) void gn_apply(const float* __restrict__ x,
                                                const float* __restrict__ stats,
                                                const float* __restrict__ gamma,
                                                const float* __restrict__ beta,
                                                bf16* __restrict__ xn) {
    size_t i = (size_t)blockIdx.x * 256 + threadIdx.x;
    size_t e = i * 4;
    int c0 = (int)(e & (Cc - 1));
    int token = (int)(e >> 9);
    int b = token >> 10;
    int g = c0 >> 4;
    float mean = stats[(b * 32 + g) * 2 + 0];
    float rstd = stats[(b * 32 + g) * 2 + 1];
    float4 t  = *(const float4*)(x + e);
    float4 gm = *(const float4*)(gamma + c0);
    float4 bt = *(const float4*)(beta + c0);
    B4 o;
    o.h[0] = __float2bfloat16((t.x - mean) * rstd * gm.x + bt.x);
    o.h[1] = __float2bfloat16((t.y - mean) * rstd * gm.y + bt.y);
    o.h[2] = __float2bfloat16((t.z - mean) * rstd * gm.z + bt.z);
    o.h[3] = __float2bfloat16((t.w - mean) * rstd * gm.w + bt.w);
    *(ushort4*)(xn + e) = o.u;
}

// ---------------------------------------------------------------------------
// 2b) Zero the padded-activation border (132 border tokens x 512 ch x 16 b)
// ---------------------------------------------------------------------------
__global__ __launch_bounds__(256) void zero_pad(bf16* __restrict__ Pad) {
    int idx = blockIdx.x * 256 + threadIdx.x;     // exactly 16*132*64
    int b = idx / (132 * 64);
    int rem = idx - b * 132 * 64;
    int t = rem >> 6, seg = rem & 63;
    int r, c;
    if (t < 34)      { r = 0;  c = t; }
    else if (t < 68) { r = 33; c = t - 34; }
    else { int u = t - 68; r = 1 + (u >> 1); c = (u & 1) * 33; }
    uint4 z = {0u, 0u, 0u, 0u};
    *(uint4*)(Pad + ((size_t)b * PIMG + r * PROW + c) * Cc + seg * 8) = z;
}

// ---------------------------------------------------------------------------
// 3) Fused QKV GEMM, m97-style: 128x128 tile, global_load_lds staging,
//    ds_read_b128 frags, 16 MFMA / wave / k-step.
//    C[16384,1536] = A[16384,512] @ Wt^T  (Wt is [n][k] bf16)
// ---------------------------------------------------------------------------
__global__ __launch_bounds__(256) void gemm_qkv(const bf16* __restrict__ A,
                                                const bf16* __restrict__ Wt,
                                                bf16* __restrict__ C) {
    __shared__ __align__(16) bf16 As[128][32];
    __shared__ __align__(16) bf16 Bs[128][32];
    int tid = threadIdx.x;
    int wave = tid >> 6, lane = tid & 63;
    int l15 = lane & 15, quad = lane >> 4;
    int wm = wave >> 1, wn = wave & 1;
    int m0 = blockIdx.y * 128, n0 = blockIdx.x * 128;
    int lr = lane >> 2, kseg = (lane & 3) * 8;
    int ar0 = wave * 32 + lr;                      // tile row staged by this lane

    const bf16* ga = A  + (size_t)(m0 + ar0) * Cc + kseg;
    const bf16* gb = Wt + (size_t)(n0 + ar0) * Cc + kseg;
    bf16* la0 = &As[wave * 32][0];
    bf16* la1 = &As[wave * 32 + 16][0];
    bf16* lb0 = &Bs[wave * 32][0];
    bf16* lb1 = &Bs[wave * 32 + 16][0];

    f32x4 acc[4][4] = {};
    for (int k0 = 0; k0 < 512; k0 += 32) {
        __syncthreads();
        stage16(ga + k0,                  la0);
        stage16(ga + k0 + (size_t)16 * Cc, la1);
        stage16(gb + k0,                  lb0);
        stage16(gb + k0 + (size_t)16 * Cc, lb1);
        __syncthreads();
        short8 af[4], bfv[4];
#pragma unroll
        for (int mt = 0; mt < 4; mt++) af[mt]  = *(const short8*)&As[wm * 64 + mt * 16 + l15][quad * 8];
#pragma unroll
        for (int nt = 0; nt < 4; nt++) bfv[nt] = *(const short8*)&Bs[wn * 64 + nt * 16 + l15][quad * 8];
#pragma unroll
        for (int mt = 0; mt < 4; mt++)
#pragma unroll
            for (int nt = 0; nt < 4; nt++)
                acc[mt][nt] = __builtin_amdgcn_mfma_f32_16x16x32_bf16(af[mt], bfv[nt], acc[mt][nt], 0, 0, 0);
    }
#pragma unroll
    for (int mt = 0; mt < 4; mt++)
#pragma unroll
        for (int r = 0; r < 4; r++) {
            size_t row = (size_t)(m0 + wm * 64 + mt * 16 + quad * 4 + r) * QKVS + n0 + wn * 64 + l15;
#pragma unroll
            for (int nt = 0; nt < 4; nt++)
                C[row + nt * 16] = __float2bfloat16(acc[mt][nt][r]);
        }
}

// ---------------------------------------------------------------------------
// 4) Flash-style MFMA attention (unchanged math); output -> padded buffer
// ---------------------------------------------------------------------------
__global__ __launch_bounds__(256) void attention_mfma(const bf16* __restrict__ QKV,
                                                      bf16* __restrict__ Pad) {
    int blk = blockIdx.x;
    int qt = blk & 15;
    int bh = blk >> 4;
    int h = bh & (HEADS - 1), b = bh >> 3;
    int tid = threadIdx.x;
    int wave = tid >> 6, lane = tid & 63;
    int l15 = lane & 15, quad = lane >> 4;

    __shared__ __align__(16) bf16 Ks[2][32][72];
    __shared__ __align__(16) bf16 Vt[2][64][40];
    __shared__ __align__(16) bf16 Ps[4][16][40];

    const size_t base = (size_t)b * Ss * QKVS + h * DHEAD;
    const bf16* kbase = QKV + base + 512;
    const bf16* vbase = QKV + base + 1024;

    int q0 = qt * 64 + wave * 16;
    const bf16* qrow = QKV + base + (size_t)(q0 + l15) * QKVS + quad * 8;
    short8 qf0 = *(const short8*)(qrow);
    short8 qf1 = *(const short8*)(qrow + 32);

    f32x4 oacc[4] = {{0.f,0.f,0.f,0.f},{0.f,0.f,0.f,0.f},{0.f,0.f,0.f,0.f},{0.f,0.f,0.f,0.f}};
    float lsum[4] = {0.f, 0.f, 0.f, 0.f};
    const f32x4 zero4 = {0.f, 0.f, 0.f, 0.f};

    int tok = tid & 31, d0 = (tid >> 5) * 8;

    uint4 nk, nv;
    {
        const size_t rb = (size_t)tok * QKVS + d0;
        nk = *(const uint4*)(kbase + rb);
        nv = *(const uint4*)(vbase + rb);
    }
    *(uint4*)&Ks[0][tok][d0] = nk;
    { U4 u; u.u = nv;
#pragma unroll
      for (int i = 0; i < 8; i++) Vt[0][d0 + i][tok] = u.h[i]; }
    __syncthreads();

    for (int c = 0; c < 32; ++c) {
        int buf = c & 1;
        if (c + 1 < 32) {
            const size_t rb = (size_t)((c + 1) * 32 + tok) * QKVS + d0;
            nk = *(const uint4*)(kbase + rb);
            nv = *(const uint4*)(vbase + rb);
        }
#pragma unroll
        for (int kg = 0; kg < 2; kg++) {
            short8 kf0 = *(const short8*)&Ks[buf][kg * 16 + l15][quad * 8];
            short8 kf1 = *(const short8*)&Ks[buf][kg * 16 + l15][32 + quad * 8];
            f32x4 s = __builtin_amdgcn_mfma_f32_16x16x32_bf16(qf0, kf0, zero4, 0, 0, 0);
            s = __builtin_amdgcn_mfma_f32_16x16x32_bf16(qf1, kf1, s, 0, 0, 0);
#pragma unroll
            for (int r = 0; r < 4; r++) {
                float p = __expf(s[r] * 0.125f);
                lsum[r] += p;
                Ps[wave][quad * 4 + r][kg * 16 + l15] = __float2bfloat16(p);
            }
        }
        short8 pf = *(const short8*)&Ps[wave][l15][quad * 8];
#pragma unroll
        for (int dt = 0; dt < 4; dt++) {
            short8 vf = *(const short8*)&Vt[buf][dt * 16 + l15][quad * 8];
            oacc[dt] = __builtin_amdgcn_mfma_f32_16x16x32_bf16(pf, vf, oacc[dt], 0, 0, 0);
        }
        if (c + 1 < 32) {
            *(uint4*)&Ks[buf ^ 1][tok][d0] = nk;
            U4 u; u.u = nv;
#pragma unroll
            for (int i = 0; i < 8; i++) Vt[buf ^ 1][d0 + i][tok] = u.h[i];
        }
        __syncthreads();
    }

#pragma unroll
    for (int r = 0; r < 4; r++) {
#pragma unroll
        for (int m = 1; m < 16; m <<= 1) lsum[r] += __shfl_xor(lsum[r], m);
    }
#pragma unroll
    for (int r = 0; r < 4; r++) {
        float inv = 1.f / lsum[r];
        int s = q0 + quad * 4 + r;
        size_t rowoff = ((size_t)(b * PROW + (s >> 5) + 1) * PROW + (s & 31) + 1) * Cc + h * DHEAD;
#pragma unroll
        for (int dt = 0; dt < 4; dt++)
            Pad[rowoff + dt * 16 + l15] = __float2bfloat16(oacc[dt][r] * inv);
    }
}

// ---------------------------------------------------------------------------
// 5) 3x3 conv as implicit GEMM, dx-tap sharing + 2-phase counted-vmcnt
//    double-buffer pipeline (T3/T4 minimum form):
//      stage(it+1) -> s_waitcnt vmcnt(8) -> s_barrier -> ds_read frags ->
//      lgkmcnt(0) + sched_barrier -> s_barrier -> 48 MFMA (pure reg)
//    Next tile's loads stay in flight across the compute phase.
// ---------------------------------------------------------------------------
__global__ __launch_bounds__(256, 2) void conv_mfma(const bf16* __restrict__ Pad,
                                                    const bf16* __restrict__ Wct,
                                                    const float* __restrict__ bias,
                                                    const float* __restrict__ xres,
                                                    float* __restrict__ out) {
    // A halo tile: 4 rows x 34 cols x 32 k (8704 B) ; B: 3 dx taps x 128 x 32
    __shared__ __align__(16) bf16 As[2][136 * 32];
    __shared__ __align__(16) bf16 Bs[2][3][128][32];

    int tid = threadIdx.x;
    int wave = tid >> 6, lane = tid & 63;
    int l15 = lane & 15, quad = lane >> 4;
    int wm = wave >> 1, wn = wave & 1;
    int m0 = blockIdx.y * 128, n0 = blockIdx.x * 128;
    int b = m0 >> 10, oh0 = (m0 & 1023) >> 5;      // block = 4 image rows of one batch

    // ---- B staging geometry (per wave: rows wave*32..+31) ----
    int lr = lane >> 2, kseg = (lane & 3) * 8;
    const bf16* gwp = Wct + (size_t)(n0 + wave * 32 + lr) * Cc + kseg;

    // ---- A staging geometry: linear chunks c = tid, tid+256, tid+512(<544) ----
    int t1 = tid >> 2,          r1 = t1 / 34, col1 = t1 - r1 * 34;
    int t2 = (tid + 256) >> 2,  r2 = t2 / 34, col2 = t2 - r2 * 34;
    int t3 = (tid + 512) >> 2,  r3 = t3 / 34, col3 = t3 - r3 * 34;
    int ks = (tid & 3) * 8;
    const size_t dyStride = (size_t)PROW * Cc;
    const bf16* pA1 = Pad + ((size_t)b * PIMG + (size_t)(oh0 + r1) * PROW + col1) * Cc + ks;
    const bf16* pA2 = Pad + ((size_t)b * PIMG + (size_t)(oh0 + r2) * PROW + col2) * Cc + ks;
    const bf16* pA3 = Pad + ((size_t)b * PIMG + (size_t)(oh0 + r3) * PROW + col3) * Cc + ks;

    // ---- A fragment row bases ----
    int arow[4];
#pragma unroll
    for (int mt = 0; mt < 4; mt++)
        arow[mt] = (wm * 2 + (mt >> 1)) * 34 + (mt & 1) * 16 + l15;

    // stage iteration 'it' (dyi = it>>4, k0 = (it&15)*32) into buffer p
    // wave0 issues 9 vmem ops, waves1-3 issue 8 -> uniform vmcnt(8) is safe
    auto stage_it = [&](int it, int p) {
        int dyi = it >> 4;
        int k0 = (it & 15) << 5;
        size_t aoff = (size_t)dyi * dyStride + k0;
        stage16(pA1 + aoff, &As[p][wave * 512]);
        stage16(pA2 + aoff, &As[p][2048 + wave * 512]);
        if (tid < 32) stage16(pA3 + aoff, &As[p][4096]);
        const bf16* gW = gwp + (size_t)(dyi * 3) * (Cc * Cc) + k0;
#pragma unroll
        for (int t = 0; t < 3; t++) {
            const bf16* gwt = gW + (size_t)t * (Cc * Cc);
            stage16(gwt,                   &Bs[p][t][wave * 32][0]);
            stage16(gwt + (size_t)16 * Cc, &Bs[p][t][wave * 32 + 16][0]);
        }
    };

    f32x4 acc[4][4] = {};
    stage_it(0, 0);
    for (int it = 0; it < 48; ++it) {
        int p = it & 1;
        if (it + 1 < 48) {
            stage_it(it + 1, p ^ 1);
            asm volatile("s_waitcnt vmcnt(8)" ::: "memory");   // this tile landed; next stays in flight
        } else {
            asm volatile("s_waitcnt vmcnt(0)" ::: "memory");
        }
        __builtin_amdgcn_s_barrier();                          // all waves: buf[p] staged

        short8 af[3][4], bfv[3][4];
#pragma unroll
        for (int dxi = 0; dxi < 3; dxi++) {
#pragma unroll
            for (int mt = 0; mt < 4; mt++)
                af[dxi][mt] = *(const short8*)&As[p][(arow[mt] + dxi) * 32 + quad * 8];
#pragma unroll
            for (int nt = 0; nt < 4; nt++)
                bfv[dxi][nt] = *(const short8*)&Bs[p][dxi][wn * 64 + nt * 16 + l15][quad * 8];
        }
        asm volatile("s_waitcnt lgkmcnt(0)" ::: "memory");     // reads landed in regs
        __builtin_amdgcn_sched_barrier(0);                     // rule #18: pin MFMA below
        __builtin_amdgcn_s_barrier();                          // read-done: next stage may overwrite buf[p]

#pragma unroll
        for (int dxi = 0; dxi < 3; dxi++)
#pragma unroll
            for (int mt = 0; mt < 4; mt++)
#pragma unroll
                for (int nt = 0; nt < 4; nt++)
                    acc[mt][nt] = __builtin_amdgcn_mfma_f32_16x16x32_bf16(af[dxi][mt], bfv[dxi][nt], acc[mt][nt], 0, 0, 0);
    }

#pragma unroll
    for (int mt = 0; mt < 4; mt++)
#pragma unroll
        for (int r = 0; r < 4; r++) {
            size_t row = (size_t)(m0 + wm * 64 + mt * 16 + quad * 4 + r) * Cc + n0 + wn * 64 + l15;
#pragma unroll
            for (int nt = 0; nt < 4; nt++) {
                int n = n0 + wn * 64 + nt * 16 + l15;
                out[row + nt * 16] = acc[mt][nt][r] + bias[n] + xres[row + nt * 16];
            }
        }
}

// ---------------------------------------------------------------------------
extern "C" void kernel_launch(void* const* d_in, const int* in_sizes, int n_in,
                              void* d_out, int out_size, void* d_ws, size_t ws_size,
                              hipStream_t stream) {
    const float* x     = (const float*)d_in[0];
    const float* gamma = (const float*)d_in[1];
    const float* beta  = (const float*)d_in[2];
    const float* wq    = (const float*)d_in[3];
    const float* wk    = (const float*)d_in[4];
    const float* wv    = (const float*)d_in[5];
    const float* convw = (const float*)d_in[6];
    const float* convb = (const float*)d_in[7];
    float* out = (float*)d_out;

    // ws layout (time-multiplexed; peak ~71.5 MiB):
    //   [0, 18.9 MiB)  : pad   (written by zero_pad+attention AFTER gemm_qkv)
    //   [0, 4 KiB)     : stats (dead before pad is written)
    //   [4 KiB, +16MiB): xn    (dead before pad is written)
    //   [xn end, +1.5M): wt    (dead before pad is written)
    //   [19 MiB, +48M) : qkv
    //   [67 MiB, +4.5M): wct
    char* ws = (char*)d_ws;
    bf16*  pad   = (bf16*)ws;
    float* stats = (float*)ws;
    bf16*  xn    = (bf16*)(ws + 4096);
    bf16*  wt    = (bf16*)(ws + 4096 + ((size_t)16 << 20));
    bf16*  qkv   = (bf16*)(ws + ((size_t)19 << 20));
    bf16*  wct   = (bf16*)(ws + ((size_t)67 << 20));

    // weight prep (dst regions distinct from src-time-live data)
    wtrans<<<dim3(128, 1), 256, 0, stream>>>(wq, wt);
    wtrans<<<dim3(128, 1), 256, 0, stream>>>(wk, wt + 262144);
    wtrans<<<dim3(128, 1), 256, 0, stream>>>(wv, wt + 524288);
    wtrans<<<dim3(128, 9), 256, 0, stream>>>(convw, wct);

    gn_stats<<<dim3(Bn * GROUPS), 256, 0, stream>>>(x, stats);
    gn_apply<<<dim3(Mtok * Cc / (4 * 256)), 256, 0, stream>>>(x, stats, gamma, beta, xn);

    gemm_qkv<<<dim3(QKVS / 128, Mtok / 128), 256, 0, stream>>>(xn, wt, qkv);

    zero_pad<<<dim3(528), 256, 0, stream>>>(pad);   // after gemm_qkv: region overlaps xn/wt
    attention_mfma<<<dim3(Bn * HEADS * (Ss / 64)), 256, 0, stream>>>(qkv, pad);

    conv_mfma<<<dim3(Cc / 128, Mtok / 128), 256, 0, stream>>>(pad, wct, convb, x, out);
}